// Round 1
// baseline (473.287 us; speedup 1.0000x reference)
//
#include <hip/hip_runtime.h>
#include <hip/hip_bf16.h>

// Problem constants (from reference)
#define DM   1024          // D_MODEL
#define NH   16            // heads
#define DH   64            // head dim per component
#define NSEQ 2048          // sequence length
#define NBATCH 2
#define ROWS (NBATCH*NSEQ) // 4096
#define QKVN (2*DM)        // 2048 = H * 2*Dh

typedef __attribute__((ext_vector_type(8))) short short8;
typedef __attribute__((ext_vector_type(4))) float f32x4;
typedef __attribute__((ext_vector_type(4))) unsigned short u16x4;

__device__ __forceinline__ unsigned short f2bf(float x) {
  union { float f; unsigned u; } v; v.f = x;
  unsigned r = v.u + 0x7FFFu + ((v.u >> 16) & 1u);
  return (unsigned short)(r >> 16);
}

__device__ __forceinline__ f32x4 mfma16(short8 a, short8 b, f32x4 c) {
  return __builtin_amdgcn_mfma_f32_16x16x32_bf16(a, b, c, 0, 0, 0);
}

// ---------------- cast X (f32 -> bf16) ----------------
__global__ void cast_f32_bf16(const float* __restrict__ in, unsigned short* __restrict__ out, int n4) {
  int i = blockIdx.x * blockDim.x + threadIdx.x;
  if (i >= n4) return;
  f32x4 v = *(const f32x4*)(in + (size_t)i * 4);
  u16x4 o;
  #pragma unroll
  for (int j = 0; j < 4; ++j) o[j] = f2bf(v[j]);
  *(u16x4*)(out + (size_t)i * 4) = o;
}

// ---------------- transpose + cast W (f32 RxC -> bf16 CxR) ----------------
__global__ void transpose_cast_w(const float* __restrict__ in, unsigned short* __restrict__ out,
                                 int R, int C) {
  __shared__ float tile[32][33];
  const int bx = blockIdx.x, by = blockIdx.y;
  const int tx = threadIdx.x, ty = threadIdx.y;
  #pragma unroll
  for (int i = 0; i < 4; ++i)
    tile[ty + i*8][tx] = in[(size_t)(by*32 + ty + i*8) * C + bx*32 + tx];
  __syncthreads();
  #pragma unroll
  for (int i = 0; i < 4; ++i)
    out[(size_t)(bx*32 + ty + i*8) * R + by*32 + tx] = f2bf(tile[tx][ty + i*8]);
}

// ---------------- transpose V (bf16 4096x2048 -> Vt[b][h][128][2048]) ----------------
__global__ void transpose_v(const unsigned short* __restrict__ Vb, unsigned short* __restrict__ Vt) {
  __shared__ unsigned short tile[32][33];
  const int bx = blockIdx.x, by = blockIdx.y;
  const int tx = threadIdx.x, ty = threadIdx.y;
  #pragma unroll
  for (int i = 0; i < 4; ++i)
    tile[ty + i*8][tx] = Vb[(size_t)(by*32 + ty + i*8) * QKVN + bx*32 + tx];
  __syncthreads();
  #pragma unroll
  for (int i = 0; i < 4; ++i) {
    int colg = bx*32 + ty + i*8;   // 0..2047  -> (h, d)
    int rowg = by*32 + tx;         // 0..4095  -> (b, n)
    int hh = colg >> 7, dd = colg & 127;
    int bb = rowg >> 11, nn = rowg & 2047;
    Vt[(size_t)((bb*NH + hh)*128 + dd) * NSEQ + nn] = tile[tx][ty + i*8];
  }
}

// ---------------- lambda per head (f32 exact) ----------------
__global__ void lam_kernel(const float* __restrict__ lq1, const float* __restrict__ lk1,
                           const float* __restrict__ lq2, const float* __restrict__ lk2,
                           float* __restrict__ lam) {
  int h = threadIdx.x >> 6, lane = threadIdx.x & 63;
  float p1 = lq1[h*64 + lane] * lk1[h*64 + lane];
  float p2 = lq2[h*64 + lane] * lk2[h*64 + lane];
  #pragma unroll
  for (int mk = 32; mk >= 1; mk >>= 1) {
    p1 += __shfl_xor(p1, mk);
    p2 += __shfl_xor(p2, mk);
  }
  if (lane == 0) lam[h] = expf(p1) - expf(p2) + 0.8f;
}

// ---------------- GEMM: C[M,N] = A[M,K] * Bt[N,K]^T  (m97 structure) ----------------
template <typename OT>
__global__ __launch_bounds__(256) void gemm_bt(const unsigned short* __restrict__ A,
                                               const unsigned short* __restrict__ Bt,
                                               OT* __restrict__ C, int M, int N, int K) {
  __shared__ __align__(16) unsigned short As[128*32];
  __shared__ __align__(16) unsigned short Bs[128*32];
  const int tid = threadIdx.x;
  const int w = tid >> 6, lane = tid & 63;
  const int l15 = lane & 15, lg = lane >> 4;
  const int wr = w >> 1, wc = w & 1;
  const int m0 = blockIdx.y * 128, n0 = blockIdx.x * 128;

  f32x4 acc[4][4];
  #pragma unroll
  for (int i = 0; i < 4; ++i)
    #pragma unroll
    for (int j = 0; j < 4; ++j) acc[i][j] = f32x4{0.f, 0.f, 0.f, 0.f};

  for (int kt = 0; kt < K; kt += 32) {
    #pragma unroll
    for (int j = 0; j < 2; ++j) {
      int cbase = (j*4 + w) * 64;          // wave-uniform chunk base
      int c = cbase + lane;                // 16B chunk id: row = c>>2, kcol = (c&3)*8
      const unsigned short* ga = A + (size_t)(m0 + (c >> 2)) * K + kt + (c & 3) * 8;
      __builtin_amdgcn_global_load_lds((const __attribute__((address_space(1))) void*)ga,
                                       (__attribute__((address_space(3))) void*)(As + cbase*8),
                                       16, 0, 0);
      const unsigned short* gb = Bt + (size_t)(n0 + (c >> 2)) * K + kt + (c & 3) * 8;
      __builtin_amdgcn_global_load_lds((const __attribute__((address_space(1))) void*)gb,
                                       (__attribute__((address_space(3))) void*)(Bs + cbase*8),
                                       16, 0, 0);
    }
    __syncthreads();
    short8 af[4], bfr[4];
    #pragma unroll
    for (int m = 0; m < 4; ++m)
      af[m] = *(const short8*)(As + (wr*64 + m*16 + l15) * 32 + lg*8);
    #pragma unroll
    for (int n = 0; n < 4; ++n)
      bfr[n] = *(const short8*)(Bs + (wc*64 + n*16 + l15) * 32 + lg*8);
    #pragma unroll
    for (int m = 0; m < 4; ++m)
      #pragma unroll
      for (int n = 0; n < 4; ++n)
        acc[m][n] = mfma16(af[m], bfr[n], acc[m][n]);
    __syncthreads();
  }

  #pragma unroll
  for (int m = 0; m < 4; ++m)
    #pragma unroll
    for (int n = 0; n < 4; ++n)
      #pragma unroll
      for (int r = 0; r < 4; ++r) {
        int row = m0 + wr*64 + m*16 + lg*4 + r;   // C/D layout: row=(lane>>4)*4+reg
        int col = n0 + wc*64 + n*16 + l15;        //             col=lane&15
        if constexpr (sizeof(OT) == 2)
          C[(size_t)row * N + col] = f2bf(acc[m][n][r]);
        else
          C[(size_t)row * N + col] = acc[m][n][r];
      }
}

// ---------------- differential flash attention + RMSNorm ----------------
// grid: (B*H, N/64), block 256 (4 independent waves, 16 q-rows each)
__global__ __launch_bounds__(256) void diff_attn(const unsigned short* __restrict__ Q,
                                                 const unsigned short* __restrict__ K,
                                                 const unsigned short* __restrict__ Vt,
                                                 const float* __restrict__ lam_arr,
                                                 const float* __restrict__ rms_scale,
                                                 unsigned short* __restrict__ O) {
  __shared__ __align__(16) unsigned short Plds[4][2][16][32];  // per-wave P staging
  const int bh = blockIdx.x;
  const int b = bh >> 4, h = bh & 15;
  const int w = threadIdx.x >> 6, lane = threadIdx.x & 63;
  const int l15 = lane & 15, lg = lane >> 4;
  const int q0 = blockIdx.y * 64 + w * 16;   // wave's first q-row
  const float lam = lam_arr[h];

  const unsigned short* Qb  = Q + (size_t)(b * NSEQ) * QKVN + h * 128;
  const unsigned short* Kb  = K + (size_t)(b * NSEQ) * QKVN + h * 128;
  const unsigned short* Vtb = Vt + (size_t)bh * 128 * NSEQ;

  // Q fragments (held whole loop): A layout lane holds Q[l15][lg*8..+8] per 32-k chunk
  short8 a1[2], a2[2];
  #pragma unroll
  for (int kc = 0; kc < 2; ++kc) {
    const unsigned short* qp = Qb + (size_t)(q0 + l15) * QKVN + kc*32 + lg*8;
    a1[kc] = *(const short8*)qp;
    a2[kc] = *(const short8*)(qp + 64);
  }

  f32x4 o1[8], o2[8];
  #pragma unroll
  for (int i = 0; i < 8; ++i) { o1[i] = f32x4{0,0,0,0}; o2[i] = f32x4{0,0,0,0}; }
  float m1[4], l1[4], m2[4], l2[4];
  #pragma unroll
  for (int r = 0; r < 4; ++r) { m1[r] = m2[r] = -3e38f; l1[r] = l2[r] = 0.f; }

  const int kb_end = (q0 + 15) >> 5;
  for (int kb = 0; kb <= kb_end; ++kb) {
    const int key0 = kb * 32;
    f32x4 s1[2], s2[2];
    #pragma unroll
    for (int nb = 0; nb < 2; ++nb) { s1[nb] = f32x4{0,0,0,0}; s2[nb] = f32x4{0,0,0,0}; }
    #pragma unroll
    for (int nb = 0; nb < 2; ++nb)
      #pragma unroll
      for (int kc = 0; kc < 2; ++kc) {
        const unsigned short* kp = Kb + (size_t)(key0 + nb*16 + l15) * QKVN + kc*32 + lg*8;
        short8 bk1 = *(const short8*)kp;
        short8 bk2 = *(const short8*)(kp + 64);
        s1[nb] = mfma16(a1[kc], bk1, s1[nb]);
        s2[nb] = mfma16(a2[kc], bk2, s2[nb]);
      }

    const bool need_mask = (key0 + 31 > q0);
    float e1v[4], e2v[4], p1v[2][4], p2v[2][4];
    #pragma unroll
    for (int r = 0; r < 4; ++r) {
      float v1a = s1[0][r] * 0.125f, v1b = s1[1][r] * 0.125f;
      float v2a = s2[0][r] * 0.125f, v2b = s2[1][r] * 0.125f;
      if (need_mask) {
        const int q = q0 + lg*4 + r;
        if (key0 + l15 > q)      { v1a = -3e38f; v2a = -3e38f; }
        if (key0 + 16 + l15 > q) { v1b = -3e38f; v2b = -3e38f; }
      }
      float t1 = fmaxf(v1a, v1b), t2 = fmaxf(v2a, v2b);
      #pragma unroll
      for (int mk = 1; mk < 16; mk <<= 1) {
        t1 = fmaxf(t1, __shfl_xor(t1, mk));
        t2 = fmaxf(t2, __shfl_xor(t2, mk));
      }
      const float mn1 = fmaxf(m1[r], t1), mn2 = fmaxf(m2[r], t2);
      const float e1 = __expf(m1[r] - mn1), e2 = __expf(m2[r] - mn2);
      float pa = __expf(v1a - mn1), pb = __expf(v1b - mn1);
      float qa = __expf(v2a - mn2), qb = __expf(v2b - mn2);
      float su1 = pa + pb, su2 = qa + qb;
      #pragma unroll
      for (int mk = 1; mk < 16; mk <<= 1) {
        su1 += __shfl_xor(su1, mk);
        su2 += __shfl_xor(su2, mk);
      }
      l1[r] = l1[r] * e1 + su1;
      l2[r] = l2[r] * e2 + su2;
      m1[r] = mn1; m2[r] = mn2;
      e1v[r] = e1; e2v[r] = e2;
      p1v[0][r] = pa; p1v[1][r] = pb;
      p2v[0][r] = qa; p2v[1][r] = qb;
    }

    #pragma unroll
    for (int i = 0; i < 8; ++i)
      #pragma unroll
      for (int r = 0; r < 4; ++r) { o1[i][r] *= e1v[r]; o2[i][r] *= e2v[r]; }

    // stage P (C-layout) -> LDS, re-read in A-layout for PV
    #pragma unroll
    for (int nb = 0; nb < 2; ++nb)
      #pragma unroll
      for (int r = 0; r < 4; ++r) {
        Plds[w][0][lg*4 + r][nb*16 + l15] = f2bf(p1v[nb][r]);
        Plds[w][1][lg*4 + r][nb*16 + l15] = f2bf(p2v[nb][r]);
      }
    asm volatile("s_waitcnt lgkmcnt(0)" ::: "memory");  // in-wave write->read fence
    __builtin_amdgcn_sched_barrier(0);
    const short8 pa1 = *(const short8*)&Plds[w][0][l15][lg*8];
    const short8 pa2 = *(const short8*)&Plds[w][1][l15][lg*8];
    __builtin_amdgcn_sched_barrier(0);

    #pragma unroll
    for (int i = 0; i < 8; ++i) {
      const short8 bv = *(const short8*)(Vtb + (size_t)(i*16 + l15) * NSEQ + key0 + lg*8);
      o1[i] = mfma16(pa1, bv, o1[i]);
      o2[i] = mfma16(pa2, bv, o2[i]);
    }
  }

  // epilogue: combine, RMSNorm over 128 dims, scale, store bf16
  float inv1[4], inv2[4];
  #pragma unroll
  for (int r = 0; r < 4; ++r) { inv1[r] = 1.f / l1[r]; inv2[r] = 1.f / l2[r]; }
  float ov[8][4];
  float ssq[4] = {0.f, 0.f, 0.f, 0.f};
  #pragma unroll
  for (int i = 0; i < 8; ++i)
    #pragma unroll
    for (int r = 0; r < 4; ++r) {
      float v = o1[i][r] * inv1[r] - lam * (o2[i][r] * inv2[r]);
      ov[i][r] = v;
      ssq[r] += v * v;
    }
  #pragma unroll
  for (int r = 0; r < 4; ++r)
    #pragma unroll
    for (int mk = 1; mk < 16; mk <<= 1) ssq[r] += __shfl_xor(ssq[r], mk);
  float rr[4];
  #pragma unroll
  for (int r = 0; r < 4; ++r) rr[r] = rsqrtf(ssq[r] * (1.f/128.f) + 1e-5f) * 0.2f;
  #pragma unroll
  for (int i = 0; i < 8; ++i) {
    const float sc = rms_scale[i*16 + l15];
    #pragma unroll
    for (int r = 0; r < 4; ++r) {
      const int q = q0 + lg*4 + r;
      O[(size_t)(b*NSEQ + q) * QKVN + h*128 + i*16 + l15] = f2bf(ov[i][r] * rr[r] * sc);
    }
  }
}

extern "C" void kernel_launch(void* const* d_in, const int* in_sizes, int n_in,
                              void* d_out, int out_size, void* d_ws, size_t ws_size,
                              hipStream_t stream) {
  (void)in_sizes; (void)n_in; (void)out_size; (void)ws_size;
  const float* X   = (const float*)d_in[0];
  const float* Wq  = (const float*)d_in[1];
  const float* Wk  = (const float*)d_in[2];
  const float* Wv  = (const float*)d_in[3];
  const float* Wo  = (const float*)d_in[4];
  const float* lq1 = (const float*)d_in[5];
  const float* lk1 = (const float*)d_in[6];
  const float* lq2 = (const float*)d_in[7];
  const float* lk2 = (const float*)d_in[8];
  const float* rs  = (const float*)d_in[9];
  float* out = (float*)d_out;

  char* ws = (char*)d_ws;
  const size_t MB = 1ull << 20;
  unsigned short* Xb  = (unsigned short*)(ws);            // 8 MB
  unsigned short* Wqt = (unsigned short*)(ws + 8*MB);     // 4 MB
  unsigned short* Wkt = (unsigned short*)(ws + 12*MB);    // 4 MB
  unsigned short* Wvt = (unsigned short*)(ws + 16*MB);    // 4 MB
  unsigned short* Wot = (unsigned short*)(ws + 20*MB);    // 4 MB
  unsigned short* Qb  = (unsigned short*)(ws + 24*MB);    // 16 MB
  unsigned short* Kb  = (unsigned short*)(ws + 40*MB);    // 16 MB
  unsigned short* Vb  = (unsigned short*)(ws + 56*MB);    // 16 MB
  unsigned short* Ob  = (unsigned short*)(ws + 72*MB);    // 16 MB
  float*          lamp = (float*)(ws + 88*MB);            // 64 B
  unsigned short* Vt  = (unsigned short*)(ws);            // 16 MB, overlays Xb/Wqt/Wkt (dead by then)

  cast_f32_bf16<<<(ROWS*DM/4 + 255)/256, 256, 0, stream>>>(X, Xb, ROWS*DM/4);
  transpose_cast_w<<<dim3(QKVN/32, DM/32), dim3(32,8), 0, stream>>>(Wq, Wqt, DM, QKVN);
  transpose_cast_w<<<dim3(QKVN/32, DM/32), dim3(32,8), 0, stream>>>(Wk, Wkt, DM, QKVN);
  transpose_cast_w<<<dim3(QKVN/32, DM/32), dim3(32,8), 0, stream>>>(Wv, Wvt, DM, QKVN);
  transpose_cast_w<<<dim3(DM/32, QKVN/32), dim3(32,8), 0, stream>>>(Wo, Wot, QKVN, DM);
  lam_kernel<<<1, 1024, 0, stream>>>(lq1, lk1, lq2, lk2, lamp);

  gemm_bt<unsigned short><<<dim3(QKVN/128, ROWS/128), 256, 0, stream>>>(Xb, Wqt, Qb, ROWS, QKVN, DM);
  gemm_bt<unsigned short><<<dim3(QKVN/128, ROWS/128), 256, 0, stream>>>(Xb, Wkt, Kb, ROWS, QKVN, DM);
  gemm_bt<unsigned short><<<dim3(QKVN/128, ROWS/128), 256, 0, stream>>>(Xb, Wvt, Vb, ROWS, QKVN, DM);

  transpose_v<<<dim3(QKVN/32, ROWS/32), dim3(32,8), 0, stream>>>(Vb, Vt);

  diff_attn<<<dim3(NBATCH*NH, NSEQ/64), 256, 0, stream>>>(Qb, Kb, Vt, lamp, rs, Ob);

  gemm_bt<float><<<dim3(DM/128, ROWS/128), 256, 0, stream>>>(Ob, Wot, out, ROWS, DM, QKVN);
}

// Round 2
// 401.053 us; speedup vs baseline: 1.1801x; 1.1801x over previous
//
#include <hip/hip_runtime.h>
#include <hip/hip_bf16.h>

// Problem constants (from reference)
#define DM   1024          // D_MODEL
#define NH   16            // heads
#define DH   64            // head dim per component
#define NSEQ 2048          // sequence length
#define NBATCH 2
#define ROWS (NBATCH*NSEQ) // 4096
#define QKVN (2*DM)        // 2048 = H * 2*Dh
#define STR3 (3*DM*2)      // 6144 = fused QKV row stride

typedef __attribute__((ext_vector_type(8))) short short8;
typedef __attribute__((ext_vector_type(4))) float f32x4;
typedef __attribute__((ext_vector_type(4))) unsigned short u16x4;

__device__ __forceinline__ unsigned short f2bf(float x) {
  union { float f; unsigned u; } v; v.f = x;
  unsigned r = v.u + 0x7FFFu + ((v.u >> 16) & 1u);
  return (unsigned short)(r >> 16);
}

__device__ __forceinline__ f32x4 mfma16(short8 a, short8 b, f32x4 c) {
  return __builtin_amdgcn_mfma_f32_16x16x32_bf16(a, b, c, 0, 0, 0);
}

// ---------------- cast X (f32 -> bf16) ----------------
__global__ void cast_f32_bf16(const float* __restrict__ in, unsigned short* __restrict__ out, int n4) {
  int i = blockIdx.x * blockDim.x + threadIdx.x;
  if (i >= n4) return;
  f32x4 v = *(const f32x4*)(in + (size_t)i * 4);
  u16x4 o;
  #pragma unroll
  for (int j = 0; j < 4; ++j) o[j] = f2bf(v[j]);
  *(u16x4*)(out + (size_t)i * 4) = o;
}

// ---------------- transpose + cast W (f32 RxC -> bf16 CxR) ----------------
__global__ void transpose_cast_w(const float* __restrict__ in, unsigned short* __restrict__ out,
                                 int R, int C) {
  __shared__ float tile[32][33];
  const int bx = blockIdx.x, by = blockIdx.y;
  const int tx = threadIdx.x, ty = threadIdx.y;
  #pragma unroll
  for (int i = 0; i < 4; ++i)
    tile[ty + i*8][tx] = in[(size_t)(by*32 + ty + i*8) * C + bx*32 + tx];
  __syncthreads();
  #pragma unroll
  for (int i = 0; i < 4; ++i)
    out[(size_t)(bx*32 + ty + i*8) * R + by*32 + tx] = f2bf(tile[tx][ty + i*8]);
}

// ---------------- transpose V slice of QKV (bf16, stride 6144) -> Vt[b][h][128][2048] ----------------
__global__ void transpose_v(const unsigned short* __restrict__ Vb, unsigned short* __restrict__ Vt) {
  __shared__ unsigned short tile[32][33];
  const int bx = blockIdx.x, by = blockIdx.y;
  const int tx = threadIdx.x, ty = threadIdx.y;
  #pragma unroll
  for (int i = 0; i < 4; ++i)
    tile[ty + i*8][tx] = Vb[(size_t)(by*32 + ty + i*8) * STR3 + bx*32 + tx];
  __syncthreads();
  #pragma unroll
  for (int i = 0; i < 4; ++i) {
    int colg = bx*32 + ty + i*8;   // 0..2047  -> (h, d)
    int rowg = by*32 + tx;         // 0..4095  -> (b, n)
    int hh = colg >> 7, dd = colg & 127;
    int bb = rowg >> 11, nn = rowg & 2047;
    Vt[(size_t)((bb*NH + hh)*128 + dd) * NSEQ + nn] = tile[tx][ty + i*8];
  }
}

// ---------------- lambda per head (f32 exact) ----------------
__global__ void lam_kernel(const float* __restrict__ lq1, const float* __restrict__ lk1,
                           const float* __restrict__ lq2, const float* __restrict__ lk2,
                           float* __restrict__ lam) {
  int h = threadIdx.x >> 6, lane = threadIdx.x & 63;
  float p1 = lq1[h*64 + lane] * lk1[h*64 + lane];
  float p2 = lq2[h*64 + lane] * lk2[h*64 + lane];
  #pragma unroll
  for (int mk = 32; mk >= 1; mk >>= 1) {
    p1 += __shfl_xor(p1, mk);
    p2 += __shfl_xor(p2, mk);
  }
  if (lane == 0) lam[h] = expf(p1) - expf(p2) + 0.8f;
}

// ---------------- GEMM: C[M,N] = A[M,K] * Bt[N,K]^T  (m97 structure) ----------------
template <typename OT>
__global__ __launch_bounds__(256) void gemm_bt(const unsigned short* __restrict__ A,
                                               const unsigned short* __restrict__ Bt,
                                               OT* __restrict__ C, int M, int N, int K) {
  __shared__ __align__(16) unsigned short As[128*32];
  __shared__ __align__(16) unsigned short Bs[128*32];
  const int tid = threadIdx.x;
  const int w = tid >> 6, lane = tid & 63;
  const int l15 = lane & 15, lg = lane >> 4;
  const int wr = w >> 1, wc = w & 1;
  const int m0 = blockIdx.y * 128, n0 = blockIdx.x * 128;

  f32x4 acc[4][4];
  #pragma unroll
  for (int i = 0; i < 4; ++i)
    #pragma unroll
    for (int j = 0; j < 4; ++j) acc[i][j] = f32x4{0.f, 0.f, 0.f, 0.f};

  for (int kt = 0; kt < K; kt += 32) {
    #pragma unroll
    for (int j = 0; j < 2; ++j) {
      int cbase = (j*4 + w) * 64;          // wave-uniform chunk base
      int c = cbase + lane;                // 16B chunk id: row = c>>2, kcol = (c&3)*8
      const unsigned short* ga = A + (size_t)(m0 + (c >> 2)) * K + kt + (c & 3) * 8;
      __builtin_amdgcn_global_load_lds((const __attribute__((address_space(1))) void*)ga,
                                       (__attribute__((address_space(3))) void*)(As + cbase*8),
                                       16, 0, 0);
      const unsigned short* gb = Bt + (size_t)(n0 + (c >> 2)) * K + kt + (c & 3) * 8;
      __builtin_amdgcn_global_load_lds((const __attribute__((address_space(1))) void*)gb,
                                       (__attribute__((address_space(3))) void*)(Bs + cbase*8),
                                       16, 0, 0);
    }
    __syncthreads();
    short8 af[4], bfr[4];
    #pragma unroll
    for (int m = 0; m < 4; ++m)
      af[m] = *(const short8*)(As + (wr*64 + m*16 + l15) * 32 + lg*8);
    #pragma unroll
    for (int n = 0; n < 4; ++n)
      bfr[n] = *(const short8*)(Bs + (wc*64 + n*16 + l15) * 32 + lg*8);
    #pragma unroll
    for (int m = 0; m < 4; ++m)
      #pragma unroll
      for (int n = 0; n < 4; ++n)
        acc[m][n] = mfma16(af[m], bfr[n], acc[m][n]);
    __syncthreads();
  }

  #pragma unroll
  for (int m = 0; m < 4; ++m)
    #pragma unroll
    for (int n = 0; n < 4; ++n)
      #pragma unroll
      for (int r = 0; r < 4; ++r) {
        int row = m0 + wr*64 + m*16 + lg*4 + r;   // C/D layout: row=(lane>>4)*4+reg
        int col = n0 + wc*64 + n*16 + l15;        //             col=lane&15
        if constexpr (sizeof(OT) == 2)
          C[(size_t)row * N + col] = f2bf(acc[m][n][r]);
        else
          C[(size_t)row * N + col] = acc[m][n][r];
      }
}

// ---------------- differential flash attention + RMSNorm ----------------
// Swapped-QK structure: S^T = mfma(Kfrag, Qfrag) -> lane l15 = q, keys along
// regs+lane-groups. Row softmax = in-register reduce + 2 shuffles. KBLK=64.
// grid: (B*H, N/64), block 256 (4 independent waves, 16 q-rows each)
__global__ __launch_bounds__(256) void diff_attn(const unsigned short* __restrict__ QKV,
                                                 const unsigned short* __restrict__ Vt,
                                                 const float* __restrict__ lam_arr,
                                                 const float* __restrict__ rms_scale,
                                                 unsigned short* __restrict__ O) {
  __shared__ __align__(16) unsigned short Plds[4][2][16*64];  // per-wave P^ staging (swizzled)
  const int bh = blockIdx.x;
  const int b = bh >> 4, h = bh & 15;
  const int w = threadIdx.x >> 6, lane = threadIdx.x & 63;
  const int l15 = lane & 15, lg = lane >> 4;
  const int yy = gridDim.y - 1 - blockIdx.y;       // longest blocks dispatch first
  const int q0 = yy * 64 + w * 16;                 // wave's first q-row
  const float lam = lam_arr[h];

  const unsigned short* Qb  = QKV + (size_t)(b * NSEQ) * STR3 + h * 128;
  const unsigned short* Kb  = QKV + (size_t)(b * NSEQ) * STR3 + 2048 + h * 128;
  const unsigned short* Vtb = Vt + (size_t)bh * 128 * NSEQ;

  // Q fragments (B-operand; rows = q): lane l15 = q, 32-k chunk per kc
  short8 a1[2], a2[2];
  #pragma unroll
  for (int kc = 0; kc < 2; ++kc) {
    const unsigned short* qp = Qb + (size_t)(q0 + l15) * STR3 + kc*32 + lg*8;
    a1[kc] = *(const short8*)qp;
    a2[kc] = *(const short8*)(qp + 64);
  }

  f32x4 o1[8], o2[8];
  #pragma unroll
  for (int i = 0; i < 8; ++i) { o1[i] = f32x4{0,0,0,0}; o2[i] = f32x4{0,0,0,0}; }
  float m1 = -3e38f, l1 = 0.f, m2 = -3e38f, l2 = 0.f;   // per-lane state for q = l15

  char* pb0 = (char*)&Plds[w][0][0];
  char* pb1 = (char*)&Plds[w][1][0];
  const unsigned swz = (unsigned)((l15 & 7) << 4);

  const int kb_end = (q0 + 15) >> 6;
  for (int kb = 0; kb <= kb_end; ++kb) {
    const int key0 = kb * 64;

    // S^T = K·Q^T : rows = keys (lg*4+r within 16-block nb), cols = q (l15)
    f32x4 st1[4], st2[4];
    #pragma unroll
    for (int nb = 0; nb < 4; ++nb) { st1[nb] = f32x4{0,0,0,0}; st2[nb] = f32x4{0,0,0,0}; }
    #pragma unroll
    for (int nb = 0; nb < 4; ++nb)
      #pragma unroll
      for (int kc = 0; kc < 2; ++kc) {
        const unsigned short* kp = Kb + (size_t)(key0 + nb*16 + l15) * STR3 + kc*32 + lg*8;
        short8 bk1 = *(const short8*)kp;
        short8 bk2 = *(const short8*)(kp + 64);
        st1[nb] = mfma16(bk1, a1[kc], st1[nb]);
        st2[nb] = mfma16(bk2, a2[kc], st2[nb]);
      }

    // scale + causal mask (per-lane: key > q)
    const bool need_mask = (key0 + 63 > q0);
    float tm1 = -3e38f, tm2 = -3e38f;
    #pragma unroll
    for (int nb = 0; nb < 4; ++nb)
      #pragma unroll
      for (int r = 0; r < 4; ++r) {
        float v1 = st1[nb][r] * 0.125f;
        float v2 = st2[nb][r] * 0.125f;
        if (need_mask && (key0 + nb*16 + lg*4 + r > q0 + l15)) { v1 = -3e38f; v2 = -3e38f; }
        st1[nb][r] = v1; st2[nb][r] = v2;
        tm1 = fmaxf(tm1, v1); tm2 = fmaxf(tm2, v2);
      }
    tm1 = fmaxf(tm1, __shfl_xor(tm1, 16));
    tm1 = fmaxf(tm1, __shfl_xor(tm1, 32));
    tm2 = fmaxf(tm2, __shfl_xor(tm2, 16));
    tm2 = fmaxf(tm2, __shfl_xor(tm2, 32));

    // defer-max (T13): rescale o only when the running max grows past THR=8
    if (__any(tm1 > m1 + 8.f)) {
      const float nm = fmaxf(m1, tm1);
      const float e = __expf(m1 - nm);
      m1 = nm; l1 *= e;
      float er[4];
      #pragma unroll
      for (int r = 0; r < 4; ++r) er[r] = __shfl(e, lg*4 + r);  // q = lg*4+r row layout
      #pragma unroll
      for (int i = 0; i < 8; ++i)
        #pragma unroll
        for (int r = 0; r < 4; ++r) o1[i][r] *= er[r];
    }
    if (__any(tm2 > m2 + 8.f)) {
      const float nm = fmaxf(m2, tm2);
      const float e = __expf(m2 - nm);
      m2 = nm; l2 *= e;
      float er[4];
      #pragma unroll
      for (int r = 0; r < 4; ++r) er[r] = __shfl(e, lg*4 + r);
      #pragma unroll
      for (int i = 0; i < 8; ++i)
        #pragma unroll
        for (int r = 0; r < 4; ++r) o2[i][r] *= er[r];
    }

    // exp + tile sums (in-register, 2 shuffles per comp)
    float ts1 = 0.f, ts2 = 0.f;
    #pragma unroll
    for (int nb = 0; nb < 4; ++nb)
      #pragma unroll
      for (int r = 0; r < 4; ++r) {
        st1[nb][r] = __expf(st1[nb][r] - m1); ts1 += st1[nb][r];
        st2[nb][r] = __expf(st2[nb][r] - m2); ts2 += st2[nb][r];
      }
    ts1 += __shfl_xor(ts1, 16); ts1 += __shfl_xor(ts1, 32); l1 += ts1;
    ts2 += __shfl_xor(ts2, 16); ts2 += __shfl_xor(ts2, 32); l2 += ts2;

    // stage P^T -> LDS [16 q][64 key] bf16, XOR-swizzled, 8B packed writes
    #pragma unroll
    for (int nb = 0; nb < 4; ++nb) {
      u16x4 k1, k2;
      #pragma unroll
      for (int r = 0; r < 4; ++r) { k1[r] = f2bf(st1[nb][r]); k2[r] = f2bf(st2[nb][r]); }
      const unsigned off = (unsigned)(l15*128 + nb*32 + lg*8) ^ swz;
      *(u16x4*)(pb0 + off) = k1;
      *(u16x4*)(pb1 + off) = k2;
    }
    asm volatile("s_waitcnt lgkmcnt(0)" ::: "memory");  // in-wave write->read fence
    __builtin_amdgcn_sched_barrier(0);
    short8 pa1[2], pa2[2];
    #pragma unroll
    for (int kc = 0; kc < 2; ++kc) {
      const unsigned off = (unsigned)(l15*128 + kc*64 + lg*16) ^ swz;
      pa1[kc] = *(const short8*)(pb0 + off);
      pa2[kc] = *(const short8*)(pb1 + off);
    }
    __builtin_amdgcn_sched_barrier(0);

    // PV: O[q][d] += P[q][key]·V[key][d]
    #pragma unroll
    for (int i = 0; i < 8; ++i)
      #pragma unroll
      for (int kc = 0; kc < 2; ++kc) {
        const short8 bv = *(const short8*)(Vtb + (size_t)(i*16 + l15) * NSEQ + key0 + kc*32 + lg*8);
        o1[i] = mfma16(pa1[kc], bv, o1[i]);
        o2[i] = mfma16(pa2[kc], bv, o2[i]);
      }
  }

  // epilogue: combine, RMSNorm over 128 dims, scale, store bf16
  float i1r[4], i2r[4];
  {
    const float inv1 = 1.f / l1, inv2 = 1.f / l2;
    #pragma unroll
    for (int r = 0; r < 4; ++r) {
      i1r[r] = __shfl(inv1, lg*4 + r);
      i2r[r] = __shfl(inv2, lg*4 + r);
    }
  }
  float ov[8][4];
  float ssq[4] = {0.f, 0.f, 0.f, 0.f};
  #pragma unroll
  for (int i = 0; i < 8; ++i)
    #pragma unroll
    for (int r = 0; r < 4; ++r) {
      float v = o1[i][r] * i1r[r] - lam * (o2[i][r] * i2r[r]);
      ov[i][r] = v;
      ssq[r] += v * v;
    }
  #pragma unroll
  for (int r = 0; r < 4; ++r)
    #pragma unroll
    for (int mk = 1; mk < 16; mk <<= 1) ssq[r] += __shfl_xor(ssq[r], mk);
  float rr[4];
  #pragma unroll
  for (int r = 0; r < 4; ++r) rr[r] = rsqrtf(ssq[r] * (1.f/128.f) + 1e-5f) * 0.2f;
  #pragma unroll
  for (int i = 0; i < 8; ++i) {
    const float sc = rms_scale[i*16 + l15];
    #pragma unroll
    for (int r = 0; r < 4; ++r) {
      const int q = q0 + lg*4 + r;
      O[(size_t)(b*NSEQ + q) * QKVN + h*128 + i*16 + l15] = f2bf(ov[i][r] * rr[r] * sc);
    }
  }
}

extern "C" void kernel_launch(void* const* d_in, const int* in_sizes, int n_in,
                              void* d_out, int out_size, void* d_ws, size_t ws_size,
                              hipStream_t stream) {
  (void)in_sizes; (void)n_in; (void)out_size; (void)ws_size;
  const float* X   = (const float*)d_in[0];
  const float* Wq  = (const float*)d_in[1];
  const float* Wk  = (const float*)d_in[2];
  const float* Wv  = (const float*)d_in[3];
  const float* Wo  = (const float*)d_in[4];
  const float* lq1 = (const float*)d_in[5];
  const float* lk1 = (const float*)d_in[6];
  const float* lq2 = (const float*)d_in[7];
  const float* lk2 = (const float*)d_in[8];
  const float* rs  = (const float*)d_in[9];
  float* out = (float*)d_out;

  char* ws = (char*)d_ws;
  const size_t MB = 1ull << 20;
  unsigned short* Xb  = (unsigned short*)(ws);            // 8 MB
  unsigned short* Wt  = (unsigned short*)(ws + 8*MB);     // 12 MB: [Wq^T; Wk^T; Wv^T] = [6144][1024]
  unsigned short* Wot = (unsigned short*)(ws + 20*MB);    // 4 MB
  unsigned short* QKV = (unsigned short*)(ws + 24*MB);    // 48 MB: [4096][6144]
  unsigned short* Ob  = (unsigned short*)(ws + 72*MB);    // 16 MB
  float*          lamp = (float*)(ws + 88*MB);            // 64 B
  unsigned short* Vt  = (unsigned short*)(ws);            // 16 MB, overlays Xb+Wt (dead by then)

  cast_f32_bf16<<<(ROWS*DM/4 + 255)/256, 256, 0, stream>>>(X, Xb, ROWS*DM/4);
  transpose_cast_w<<<dim3(QKVN/32, DM/32), dim3(32,8), 0, stream>>>(Wq, Wt,            DM, QKVN);
  transpose_cast_w<<<dim3(QKVN/32, DM/32), dim3(32,8), 0, stream>>>(Wk, Wt + 2048*1024, DM, QKVN);
  transpose_cast_w<<<dim3(QKVN/32, DM/32), dim3(32,8), 0, stream>>>(Wv, Wt + 4096*1024, DM, QKVN);
  transpose_cast_w<<<dim3(DM/32, QKVN/32), dim3(32,8), 0, stream>>>(Wo, Wot, QKVN, DM);
  lam_kernel<<<1, 1024, 0, stream>>>(lq1, lk1, lq2, lk2, lamp);

  // fused QKV projection: [4096][1024] x [6144][1024]^T -> [4096][6144]
  gemm_bt<unsigned short><<<dim3(STR3/128, ROWS/128), 256, 0, stream>>>(Xb, Wt, QKV, ROWS, STR3, DM);

  transpose_v<<<dim3(QKVN/32, ROWS/32), dim3(32,8), 0, stream>>>(QKV + 4096, Vt);

  diff_attn<<<dim3(NBATCH*NH, NSEQ/64), 256, 0, stream>>>(QKV, Vt, lamp, rs, Ob);

  gemm_bt<float><<<dim3(DM/128, ROWS/128), 256, 0, stream>>>(Ob, Wot, out, ROWS, DM, QKVN);
}

// Round 3
// 253.549 us; speedup vs baseline: 1.8667x; 1.5818x over previous
//
#include <hip/hip_runtime.h>
#include <hip/hip_bf16.h>

// Problem constants (from reference)
#define DM   1024          // D_MODEL
#define NH   16            // heads
#define DH   64            // head dim per component
#define NSEQ 2048          // sequence length
#define NBATCH 2
#define ROWS (NBATCH*NSEQ) // 4096
#define QKVN (2*DM)        // 2048 = H * 2*Dh
#define STR3 (3*DM*2)      // 6144 = fused QKV row stride

typedef __attribute__((ext_vector_type(8))) short short8;
typedef __attribute__((ext_vector_type(4))) float f32x4;
typedef __attribute__((ext_vector_type(4))) unsigned short u16x4;

__device__ __forceinline__ unsigned short f2bf(float x) {
  union { float f; unsigned u; } v; v.f = x;
  unsigned r = v.u + 0x7FFFu + ((v.u >> 16) & 1u);
  return (unsigned short)(r >> 16);
}

__device__ __forceinline__ f32x4 mfma16(short8 a, short8 b, f32x4 c) {
  return __builtin_amdgcn_mfma_f32_16x16x32_bf16(a, b, c, 0, 0, 0);
}

#define GLL(src, dst) \
  __builtin_amdgcn_global_load_lds((const __attribute__((address_space(1))) void*)(src), \
                                   (__attribute__((address_space(3))) void*)(dst), 16, 0, 0)

// ---------------- cast X (f32 -> bf16) ----------------
__global__ void cast_f32_bf16(const float* __restrict__ in, unsigned short* __restrict__ out, int n4) {
  int i = blockIdx.x * blockDim.x + threadIdx.x;
  if (i >= n4) return;
  f32x4 v = *(const f32x4*)(in + (size_t)i * 4);
  u16x4 o;
  #pragma unroll
  for (int j = 0; j < 4; ++j) o[j] = f2bf(v[j]);
  *(u16x4*)(out + (size_t)i * 4) = o;
}

// ---------------- transpose + cast W (f32 RxC -> bf16 CxR) ----------------
__global__ void transpose_cast_w(const float* __restrict__ in, unsigned short* __restrict__ out,
                                 int R, int C) {
  __shared__ float tile[32][33];
  const int bx = blockIdx.x, by = blockIdx.y;
  const int tx = threadIdx.x, ty = threadIdx.y;
  #pragma unroll
  for (int i = 0; i < 4; ++i)
    tile[ty + i*8][tx] = in[(size_t)(by*32 + ty + i*8) * C + bx*32 + tx];
  __syncthreads();
  #pragma unroll
  for (int i = 0; i < 4; ++i)
    out[(size_t)(bx*32 + ty + i*8) * R + by*32 + tx] = f2bf(tile[tx][ty + i*8]);
}

// ---------------- transpose V slice of QKV (bf16, stride 6144) -> Vt[b][h][128][2048] ----------------
__global__ void transpose_v(const unsigned short* __restrict__ Vb, unsigned short* __restrict__ Vt) {
  __shared__ unsigned short tile[32][33];
  const int bx = blockIdx.x, by = blockIdx.y;
  const int tx = threadIdx.x, ty = threadIdx.y;
  #pragma unroll
  for (int i = 0; i < 4; ++i)
    tile[ty + i*8][tx] = Vb[(size_t)(by*32 + ty + i*8) * STR3 + bx*32 + tx];
  __syncthreads();
  #pragma unroll
  for (int i = 0; i < 4; ++i) {
    int colg = bx*32 + ty + i*8;   // 0..2047  -> (h, d)
    int rowg = by*32 + tx;         // 0..4095  -> (b, n)
    int hh = colg >> 7, dd = colg & 127;
    int bb = rowg >> 11, nn = rowg & 2047;
    Vt[(size_t)((bb*NH + hh)*128 + dd) * NSEQ + nn] = tile[tx][ty + i*8];
  }
}

// ---------------- lambda per head (f32 exact) ----------------
__global__ void lam_kernel(const float* __restrict__ lq1, const float* __restrict__ lk1,
                           const float* __restrict__ lq2, const float* __restrict__ lk2,
                           float* __restrict__ lam) {
  int h = threadIdx.x >> 6, lane = threadIdx.x & 63;
  float p1 = lq1[h*64 + lane] * lk1[h*64 + lane];
  float p2 = lq2[h*64 + lane] * lk2[h*64 + lane];
  #pragma unroll
  for (int mk = 32; mk >= 1; mk >>= 1) {
    p1 += __shfl_xor(p1, mk);
    p2 += __shfl_xor(p2, mk);
  }
  if (lane == 0) lam[h] = expf(p1) - expf(p2) + 0.8f;
}

// ---------------- GEMM: C[M,N] = A[M,K] * Bt[N,K]^T  (m97 structure) ----------------
template <typename OT>
__global__ __launch_bounds__(256) void gemm_bt(const unsigned short* __restrict__ A,
                                               const unsigned short* __restrict__ Bt,
                                               OT* __restrict__ C, int M, int N, int K) {
  __shared__ __align__(16) unsigned short As[128*32];
  __shared__ __align__(16) unsigned short Bs[128*32];
  const int tid = threadIdx.x;
  const int w = tid >> 6, lane = tid & 63;
  const int l15 = lane & 15, lg = lane >> 4;
  const int wr = w >> 1, wc = w & 1;
  const int m0 = blockIdx.y * 128, n0 = blockIdx.x * 128;

  f32x4 acc[4][4];
  #pragma unroll
  for (int i = 0; i < 4; ++i)
    #pragma unroll
    for (int j = 0; j < 4; ++j) acc[i][j] = f32x4{0.f, 0.f, 0.f, 0.f};

  for (int kt = 0; kt < K; kt += 32) {
    #pragma unroll
    for (int j = 0; j < 2; ++j) {
      int cbase = (j*4 + w) * 64;          // wave-uniform chunk base
      int c = cbase + lane;                // 16B chunk id: row = c>>2, kcol = (c&3)*8
      const unsigned short* ga = A + (size_t)(m0 + (c >> 2)) * K + kt + (c & 3) * 8;
      GLL(ga, As + cbase*8);
      const unsigned short* gb = Bt + (size_t)(n0 + (c >> 2)) * K + kt + (c & 3) * 8;
      GLL(gb, Bs + cbase*8);
    }
    __syncthreads();
    short8 af[4], bfr[4];
    #pragma unroll
    for (int m = 0; m < 4; ++m)
      af[m] = *(const short8*)(As + (wr*64 + m*16 + l15) * 32 + lg*8);
    #pragma unroll
    for (int n = 0; n < 4; ++n)
      bfr[n] = *(const short8*)(Bs + (wc*64 + n*16 + l15) * 32 + lg*8);
    #pragma unroll
    for (int m = 0; m < 4; ++m)
      #pragma unroll
      for (int n = 0; n < 4; ++n)
        acc[m][n] = mfma16(af[m], bfr[n], acc[m][n]);
    __syncthreads();
  }

  #pragma unroll
  for (int m = 0; m < 4; ++m)
    #pragma unroll
    for (int n = 0; n < 4; ++n)
      #pragma unroll
      for (int r = 0; r < 4; ++r) {
        int row = m0 + wr*64 + m*16 + lg*4 + r;   // C/D layout: row=(lane>>4)*4+reg
        int col = n0 + wc*64 + n*16 + l15;        //             col=lane&15
        if constexpr (sizeof(OT) == 2)
          C[(size_t)row * N + col] = f2bf(acc[m][n][r]);
        else
          C[(size_t)row * N + col] = acc[m][n][r];
      }
}

// ---------------- differential flash attention + RMSNorm ----------------
// Swapped-QK + block-shared double-buffered K/V LDS staging (T3-min 2-phase).
// All 4 waves of a block have identical trip counts (kb_end = yy for w=0..3),
// so block-wide __syncthreads() pipelining is legal.
// K tile [64 key][128 d], V tile [128 d][64 key], both XOR-swizzled
// (chunk ^ (row&7)) with pre-swizzled global source (rule #21).
// grid: (B*H, N/64), block 256 (4 waves, 16 q-rows each)
__global__ __launch_bounds__(256) void diff_attn(const unsigned short* __restrict__ QKV,
                                                 const unsigned short* __restrict__ Vt,
                                                 const float* __restrict__ lam_arr,
                                                 const float* __restrict__ rms_scale,
                                                 unsigned short* __restrict__ O) {
  __shared__ __align__(16) unsigned short Ks[2][64*128];   // 32 KB
  __shared__ __align__(16) unsigned short Vs[2][128*64];   // 32 KB
  __shared__ __align__(16) unsigned short Plds[4][2][16*64]; // 16 KB per-wave P staging
  const int bh = blockIdx.x;
  const int b = bh >> 4, h = bh & 15;
  const int w = threadIdx.x >> 6, lane = threadIdx.x & 63;
  const int l15 = lane & 15, lg = lane >> 4;
  const int yy = gridDim.y - 1 - blockIdx.y;       // longest blocks dispatch first
  const int q0 = yy * 64 + w * 16;                 // wave's first q-row
  const float lam = lam_arr[h];

  const unsigned short* Qb  = QKV + (size_t)(b * NSEQ) * STR3 + h * 128;
  const unsigned short* Kb  = QKV + (size_t)(b * NSEQ) * STR3 + 2048 + h * 128;
  const unsigned short* Vtb = Vt + (size_t)bh * 128 * NSEQ;

  // Q fragments (B-operand; lane l15 = q), held whole loop
  short8 a1[2], a2[2];
  #pragma unroll
  for (int kc = 0; kc < 2; ++kc) {
    const unsigned short* qp = Qb + (size_t)(q0 + l15) * STR3 + kc*32 + lg*8;
    a1[kc] = *(const short8*)qp;
    a2[kc] = *(const short8*)(qp + 64);
  }

  // stage one 64-key K/V tile into LDS buffer bufi (8 global_load_lds per wave)
  auto stage = [&](int bufi, int key0) {
    #pragma unroll
    for (int j = 0; j < 4; ++j) {
      const int t = j*4 + w;
      {  // K: 16 chunks/row, 4 rows per 1KB instr
        const int row = t*4 + (lane >> 4);
        const int ck  = lane & 15;
        const int cks = (ck & 8) | ((ck ^ row) & 7);
        GLL(Kb + (size_t)(key0 + row) * STR3 + cks*8, &Ks[bufi][t*512]);
      }
      {  // V: 8 chunks/row, 8 rows per 1KB instr
        const int row = t*8 + (lane >> 3);
        const int ck  = lane & 7;
        const int cks = (ck ^ row) & 7;
        GLL(Vtb + (size_t)row * NSEQ + key0 + cks*8, &Vs[bufi][t*512]);
      }
    }
  };

  f32x4 o1[8], o2[8];
  #pragma unroll
  for (int i = 0; i < 8; ++i) { o1[i] = f32x4{0,0,0,0}; o2[i] = f32x4{0,0,0,0}; }
  float m1 = -3e38f, l1 = 0.f, m2 = -3e38f, l2 = 0.f;   // per-lane state for q = l15

  char* pb0 = (char*)&Plds[w][0][0];
  char* pb1 = (char*)&Plds[w][1][0];
  const unsigned swz = (unsigned)((l15 & 7) << 4);

  stage(0, 0);
  __syncthreads();            // drains vmcnt(0) then barrier
  int buf = 0;

  for (int kb = 0; kb <= yy; ++kb) {
    const int key0 = kb * 64;
    if (kb < yy) stage(buf ^ 1, key0 + 64);   // async prefetch of next tile

    // S^T = K·Q^T from LDS K (swizzled reads)
    f32x4 st1[4], st2[4];
    #pragma unroll
    for (int nb = 0; nb < 4; ++nb) { st1[nb] = f32x4{0,0,0,0}; st2[nb] = f32x4{0,0,0,0}; }
    __builtin_amdgcn_s_setprio(1);
    #pragma unroll
    for (int nb = 0; nb < 4; ++nb) {
      const int row = nb*16 + l15;
      #pragma unroll
      for (int kc = 0; kc < 2; ++kc) {
        const unsigned short* kp = &Ks[buf][row*128 + (((kc*4 + lg) ^ row) & 7) * 8];
        short8 bk1 = *(const short8*)kp;
        short8 bk2 = *(const short8*)(kp + 64);   // comp2 = chunk+8, same low-3 xor
        st1[nb] = mfma16(bk1, a1[kc], st1[nb]);
        st2[nb] = mfma16(bk2, a2[kc], st2[nb]);
      }
    }
    __builtin_amdgcn_s_setprio(0);

    // scale + causal mask (per-lane: key > q)
    const bool need_mask = (key0 + 63 > q0);
    float tm1 = -3e38f, tm2 = -3e38f;
    #pragma unroll
    for (int nb = 0; nb < 4; ++nb)
      #pragma unroll
      for (int r = 0; r < 4; ++r) {
        float v1 = st1[nb][r] * 0.125f;
        float v2 = st2[nb][r] * 0.125f;
        if (need_mask && (key0 + nb*16 + lg*4 + r > q0 + l15)) { v1 = -3e38f; v2 = -3e38f; }
        st1[nb][r] = v1; st2[nb][r] = v2;
        tm1 = fmaxf(tm1, v1); tm2 = fmaxf(tm2, v2);
      }
    tm1 = fmaxf(tm1, __shfl_xor(tm1, 16));
    tm1 = fmaxf(tm1, __shfl_xor(tm1, 32));
    tm2 = fmaxf(tm2, __shfl_xor(tm2, 16));
    tm2 = fmaxf(tm2, __shfl_xor(tm2, 32));

    // defer-max (T13): rescale o only when the running max grows past THR=8
    if (__any(tm1 > m1 + 8.f)) {
      const float nm = fmaxf(m1, tm1);
      const float e = __expf(m1 - nm);
      m1 = nm; l1 *= e;
      float er[4];
      #pragma unroll
      for (int r = 0; r < 4; ++r) er[r] = __shfl(e, lg*4 + r);
      #pragma unroll
      for (int i = 0; i < 8; ++i)
        #pragma unroll
        for (int r = 0; r < 4; ++r) o1[i][r] *= er[r];
    }
    if (__any(tm2 > m2 + 8.f)) {
      const float nm = fmaxf(m2, tm2);
      const float e = __expf(m2 - nm);
      m2 = nm; l2 *= e;
      float er[4];
      #pragma unroll
      for (int r = 0; r < 4; ++r) er[r] = __shfl(e, lg*4 + r);
      #pragma unroll
      for (int i = 0; i < 8; ++i)
        #pragma unroll
        for (int r = 0; r < 4; ++r) o2[i][r] *= er[r];
    }

    // exp + tile sums (in-register, 2 shuffles per comp)
    float ts1 = 0.f, ts2 = 0.f;
    #pragma unroll
    for (int nb = 0; nb < 4; ++nb)
      #pragma unroll
      for (int r = 0; r < 4; ++r) {
        st1[nb][r] = __expf(st1[nb][r] - m1); ts1 += st1[nb][r];
        st2[nb][r] = __expf(st2[nb][r] - m2); ts2 += st2[nb][r];
      }
    ts1 += __shfl_xor(ts1, 16); ts1 += __shfl_xor(ts1, 32); l1 += ts1;
    ts2 += __shfl_xor(ts2, 16); ts2 += __shfl_xor(ts2, 32); l2 += ts2;

    // stage P^T -> per-wave LDS [16 q][64 key] bf16, XOR-swizzled, 8B writes
    #pragma unroll
    for (int nb = 0; nb < 4; ++nb) {
      u16x4 k1, k2;
      #pragma unroll
      for (int r = 0; r < 4; ++r) { k1[r] = f2bf(st1[nb][r]); k2[r] = f2bf(st2[nb][r]); }
      const unsigned off = (unsigned)(l15*128 + nb*32 + lg*8) ^ swz;
      *(u16x4*)(pb0 + off) = k1;
      *(u16x4*)(pb1 + off) = k2;
    }
    asm volatile("s_waitcnt lgkmcnt(0)" ::: "memory");  // in-wave write->read fence
    __builtin_amdgcn_sched_barrier(0);
    short8 pa1[2], pa2[2];
    #pragma unroll
    for (int kc = 0; kc < 2; ++kc) {
      const unsigned off = (unsigned)(l15*128 + kc*64 + lg*16) ^ swz;
      pa1[kc] = *(const short8*)(pb0 + off);
      pa2[kc] = *(const short8*)(pb1 + off);
    }
    __builtin_amdgcn_sched_barrier(0);

    // PV: O[q][d] += P[q][key]·V[key][d] from LDS V (swizzled reads)
    __builtin_amdgcn_s_setprio(1);
    #pragma unroll
    for (int i = 0; i < 8; ++i) {
      const int row = i*16 + l15;
      #pragma unroll
      for (int kc = 0; kc < 2; ++kc) {
        const short8 bv = *(const short8*)(&Vs[buf][row*64 + (((kc*4 + lg) ^ row) & 7) * 8]);
        o1[i] = mfma16(pa1[kc], bv, o1[i]);
        o2[i] = mfma16(pa2[kc], bv, o2[i]);
      }
    }
    __builtin_amdgcn_s_setprio(0);

    __syncthreads();           // drains prefetch vmcnt + guards buffer swap
    buf ^= 1;
  }

  // epilogue: combine, RMSNorm over 128 dims, scale, store bf16
  float i1r[4], i2r[4];
  {
    const float inv1 = 1.f / l1, inv2 = 1.f / l2;
    #pragma unroll
    for (int r = 0; r < 4; ++r) {
      i1r[r] = __shfl(inv1, lg*4 + r);
      i2r[r] = __shfl(inv2, lg*4 + r);
    }
  }
  float ov[8][4];
  float ssq[4] = {0.f, 0.f, 0.f, 0.f};
  #pragma unroll
  for (int i = 0; i < 8; ++i)
    #pragma unroll
    for (int r = 0; r < 4; ++r) {
      float v = o1[i][r] * i1r[r] - lam * (o2[i][r] * i2r[r]);
      ov[i][r] = v;
      ssq[r] += v * v;
    }
  #pragma unroll
  for (int r = 0; r < 4; ++r)
    #pragma unroll
    for (int mk = 1; mk < 16; mk <<= 1) ssq[r] += __shfl_xor(ssq[r], mk);
  float rr[4];
  #pragma unroll
  for (int r = 0; r < 4; ++r) rr[r] = rsqrtf(ssq[r] * (1.f/128.f) + 1e-5f) * 0.2f;
  #pragma unroll
  for (int i = 0; i < 8; ++i) {
    const float sc = rms_scale[i*16 + l15];
    #pragma unroll
    for (int r = 0; r < 4; ++r) {
      const int q = q0 + lg*4 + r;
      O[(size_t)(b*NSEQ + q) * QKVN + h*128 + i*16 + l15] = f2bf(ov[i][r] * rr[r] * sc);
    }
  }
}

extern "C" void kernel_launch(void* const* d_in, const int* in_sizes, int n_in,
                              void* d_out, int out_size, void* d_ws, size_t ws_size,
                              hipStream_t stream) {
  (void)in_sizes; (void)n_in; (void)out_size; (void)ws_size;
  const float* X   = (const float*)d_in[0];
  const float* Wq  = (const float*)d_in[1];
  const float* Wk  = (const float*)d_in[2];
  const float* Wv  = (const float*)d_in[3];
  const float* Wo  = (const float*)d_in[4];
  const float* lq1 = (const float*)d_in[5];
  const float* lk1 = (const float*)d_in[6];
  const float* lq2 = (const float*)d_in[7];
  const float* lk2 = (const float*)d_in[8];
  const float* rs  = (const float*)d_in[9];
  float* out = (float*)d_out;

  char* ws = (char*)d_ws;
  const size_t MB = 1ull << 20;
  unsigned short* Xb  = (unsigned short*)(ws);            // 8 MB
  unsigned short* Wt  = (unsigned short*)(ws + 8*MB);     // 12 MB: [Wq^T; Wk^T; Wv^T] = [6144][1024]
  unsigned short* Wot = (unsigned short*)(ws + 20*MB);    // 4 MB
  unsigned short* QKV = (unsigned short*)(ws + 24*MB);    // 48 MB: [4096][6144]
  unsigned short* Ob  = (unsigned short*)(ws + 72*MB);    // 16 MB
  float*          lamp = (float*)(ws + 88*MB);            // 64 B
  unsigned short* Vt  = (unsigned short*)(ws);            // 16 MB, overlays Xb+Wt (dead by then)

  cast_f32_bf16<<<(ROWS*DM/4 + 255)/256, 256, 0, stream>>>(X, Xb, ROWS*DM/4);
  transpose_cast_w<<<dim3(QKVN/32, DM/32), dim3(32,8), 0, stream>>>(Wq, Wt,             DM, QKVN);
  transpose_cast_w<<<dim3(QKVN/32, DM/32), dim3(32,8), 0, stream>>>(Wk, Wt + 2048*1024, DM, QKVN);
  transpose_cast_w<<<dim3(QKVN/32, DM/32), dim3(32,8), 0, stream>>>(Wv, Wt + 4096*1024, DM, QKVN);
  transpose_cast_w<<<dim3(DM/32, QKVN/32), dim3(32,8), 0, stream>>>(Wo, Wot, QKVN, DM);
  lam_kernel<<<1, 1024, 0, stream>>>(lq1, lk1, lq2, lk2, lamp);

  // fused QKV projection: [4096][1024] x [6144][1024]^T -> [4096][6144]
  gemm_bt<unsigned short><<<dim3(STR3/128, ROWS/128), 256, 0, stream>>>(Xb, Wt, QKV, ROWS, STR3, DM);

  transpose_v<<<dim3(QKVN/32, ROWS/32), dim3(32,8), 0, stream>>>(QKV + 4096, Vt);

  diff_attn<<<dim3(NBATCH*NH, NSEQ/64), 256, 0, stream>>>(QKV, Vt, lamp, rs, Ob);

  gemm_bt<float><<<dim3(DM/128, ROWS/128), 256, 0, stream>>>(Ob, Wot, out, ROWS, DM, QKVN);
}